// Round 1
// baseline (4672.052 us; speedup 1.0000x reference)
//
#include <hip/hip_runtime.h>
#include <stdint.h>

#define MAX_PROPOSALS 1000
#define WPAD 160   // padded 64-bit words per mask row; layout requires W <= 160

// ---------------------------------------------------------------------------
// K1: stable argsort by descending score via rank counting.
// rank(i) = #{j : s_j > s_i} + #{j : s_j == s_i && j < i}   (matches stable
// jnp.argsort(-scores)). Each block stages all scores in LDS (broadcast reads).
// Scatters boxes/scores into sorted SoA arrays.
// ---------------------------------------------------------------------------
__global__ void k_sort(const float* __restrict__ boxes, const float* __restrict__ scores,
                       float* __restrict__ sx1, float* __restrict__ sy1,
                       float* __restrict__ sx2, float* __restrict__ sy2,
                       float* __restrict__ ss, int N) {
  extern __shared__ float sh[];
  for (int j = threadIdx.x; j < N; j += blockDim.x) sh[j] = scores[j];
  __syncthreads();
  int i = blockIdx.x * blockDim.x + threadIdx.x;
  if (i >= N) return;
  float si = sh[i];
  int rank = 0;
  int j = 0;
  for (; j + 4 <= N; j += 4) {
    float a = sh[j], b = sh[j + 1], c = sh[j + 2], d = sh[j + 3];
    rank += (a > si) || (a == si && (j    ) < i);
    rank += (b > si) || (b == si && (j + 1) < i);
    rank += (c > si) || (c == si && (j + 2) < i);
    rank += (d > si) || (d == si && (j + 3) < i);
  }
  for (; j < N; ++j) {
    float a = sh[j];
    rank += (a > si) || (a == si && j < i);
  }
  sx1[rank] = boxes[4 * i + 0];
  sy1[rank] = boxes[4 * i + 1];
  sx2[rank] = boxes[4 * i + 2];
  sy2[rank] = boxes[4 * i + 3];
  ss[rank]  = si;
}

// ---------------------------------------------------------------------------
// K2: suppression bitmask. Block = (col-word cb, row-block rb), 64 threads,
// thread = one row. bits(jj) = (j > row) && (j < N) && IoU(row, j) > 0.5.
// IoU uses the reference's exact fp32 op sequence (no FMA-able patterns,
// true division) so decisions match bitwise.
// ---------------------------------------------------------------------------
__global__ __launch_bounds__(64) void k_mask(const float* __restrict__ sx1, const float* __restrict__ sy1,
                        const float* __restrict__ sx2, const float* __restrict__ sy2,
                        uint64_t* __restrict__ mask, int N) {
  int cb = blockIdx.x;            // column word index, 0..WPAD-1
  int rb = blockIdx.y;            // row block, 0..W-1
  int l  = threadIdx.x;           // 0..63
  int row = rb * 64 + l;

  __shared__ float cx1[64], cy1[64], cx2[64], cy2[64], car[64];
  int c = cb * 64 + l;
  if (c < N) {
    float a = sx1[c], b = sy1[c], x = sx2[c], y = sy2[c];
    cx1[l] = a; cy1[l] = b; cx2[l] = x; cy2[l] = y;
    car[l] = (x - a) * (y - b);
  } else {
    cx1[l] = 0.0f; cy1[l] = 0.0f; cx2[l] = 0.0f; cy2[l] = 0.0f; car[l] = 0.0f;
  }
  __syncthreads();

  if (row >= N) return;

  uint64_t bits = 0;
  int cbase = cb * 64;
  if (cbase + 63 > row) {         // otherwise every j <= row -> bits stay 0
    float x1 = sx1[row], y1 = sy1[row], x2 = sx2[row], y2 = sy2[row];
    float ar = (x2 - x1) * (y2 - y1);
    for (int jj = 0; jj < 64; ++jj) {
      int j = cbase + jj;
      float ix1 = fmaxf(x1, cx1[jj]);
      float iy1 = fmaxf(y1, cy1[jj]);
      float ix2 = fminf(x2, cx2[jj]);
      float iy2 = fminf(y2, cy2[jj]);
      float iw = fmaxf(ix2 - ix1, 0.0f);
      float ih = fmaxf(iy2 - iy1, 0.0f);
      float inter = iw * ih;
      float uni = ar + car[jj] - inter;
      float iou = inter / fmaxf(uni, 1e-9f);
      if (j > row && j < N && iou > 0.5f) bits |= (1ull << jj);
    }
  }
  mask[(size_t)row * WPAD + cb] = bits;
}

// ---------------------------------------------------------------------------
// K3: sequential greedy scan, ONE wave (64 threads), keep bitmask in REGISTERS:
// lane l owns words 2l, 2l+1 (k0,k1) and, if l<16, words 128+2l, 129+2l (k2,k3).
// Replicated-current-word trick: every lane loads row i's word (i>>6) (same
// address -> one request) and keeps an identical copy `cur` of the in-flight
// keep word, so the per-iteration bit test is pure lane-local ALU; cross-lane
// __shfl only once per 64 iterations. Row loads are unconditional so they can
// be pipelined; application is masked by sel.
// ---------------------------------------------------------------------------
__device__ __forceinline__ uint64_t shfl_u64(uint64_t v, int lane) {
  int lo = __shfl((int)(unsigned int)v, lane, 64);
  int hi = __shfl((int)(unsigned int)(v >> 32), lane, 64);
  return ((uint64_t)(unsigned int)hi << 32) | (uint64_t)(unsigned int)lo;
}

__global__ __launch_bounds__(64) void k_scan(const uint64_t* __restrict__ mask,
                                             uint64_t* __restrict__ keep_out,
                                             int* __restrict__ wpref, int N) {
  int l = threadIdx.x;
  uint64_t k0 = ~0ull, k1 = ~0ull, k2 = ~0ull, k3 = ~0ull;
  int nw = (N + 63) >> 6;

  for (int w = 0; w < nw; ++w) {
    // refresh replicated copy of keep word w from its owner lane
    uint64_t mine = (w < 128) ? ((w & 1) ? k1 : k0) : ((w & 1) ? k3 : k2);
    int owner = (w < 128) ? (w >> 1) : ((w - 128) >> 1);
    uint64_t cur = shfl_u64(mine, owner);

    int i0 = w << 6;
    if (i0 + 64 <= N) {
      #pragma unroll
      for (int b = 0; b < 64; ++b) {
        const uint64_t* rp = mask + (size_t)(i0 + b) * WPAD;
        uint64_t mw = rp[w];                                   // uniform addr
        ulonglong2 ra = *(const ulonglong2*)(rp + 2 * l);      // words 2l,2l+1
        ulonglong2 rb2;
        if (l < 16) rb2 = *(const ulonglong2*)(rp + 128 + 2 * l);
        else { rb2.x = 0; rb2.y = 0; }
        uint64_t sel = ((cur >> b) & 1ull) ? ~0ull : 0ull;
        k0 &= ~(ra.x  & sel);
        k1 &= ~(ra.y  & sel);
        k2 &= ~(rb2.x & sel);
        k3 &= ~(rb2.y & sel);
        cur &= ~(mw & sel);
      }
    } else {
      int iend = N - i0;
      for (int b = 0; b < iend; ++b) {
        const uint64_t* rp = mask + (size_t)(i0 + b) * WPAD;
        uint64_t mw = rp[w];
        ulonglong2 ra = *(const ulonglong2*)(rp + 2 * l);
        ulonglong2 rb2;
        if (l < 16) rb2 = *(const ulonglong2*)(rp + 128 + 2 * l);
        else { rb2.x = 0; rb2.y = 0; }
        uint64_t sel = ((cur >> b) & 1ull) ? ~0ull : 0ull;
        k0 &= ~(ra.x  & sel);
        k1 &= ~(ra.y  & sel);
        k2 &= ~(rb2.x & sel);
        k3 &= ~(rb2.y & sel);
        cur &= ~(mw & sel);
      }
    }
  }

  // mask off tail bits >= N, publish keep words + per-word popcount prefix
  auto fix = [&](uint64_t& k, int wi) {
    long long lo = (long long)wi * 64;
    if (lo >= N) { k = 0; return; }
    int rem = N - (int)lo;
    if (rem < 64) k &= ((1ull << rem) - 1ull);
  };
  fix(k0, 2 * l); fix(k1, 2 * l + 1);
  fix(k2, 128 + 2 * l); fix(k3, 129 + 2 * l);

  keep_out[2 * l] = k0;
  keep_out[2 * l + 1] = k1;
  if (l < 16) { keep_out[128 + 2 * l] = k2; keep_out[129 + 2 * l] = k3; }

  __shared__ int cnt[WPAD];
  cnt[2 * l] = __popcll(k0);
  cnt[2 * l + 1] = __popcll(k1);
  if (l < 16) { cnt[128 + 2 * l] = __popcll(k2); cnt[129 + 2 * l] = __popcll(k3); }
  __syncthreads();
  if (l == 0) {
    int run = 0;
    for (int t = 0; t < WPAD; ++t) { wpref[t] = run; run += cnt[t]; }
  }
}

// ---------------------------------------------------------------------------
// K4: ranks via popcount prefix, MAX_PROPOSALS cutoff, write outputs.
// Output layout: boxes (N*4) | scores (N) | keep-as-float (N).
// ---------------------------------------------------------------------------
__global__ void k_out(const float* __restrict__ sx1, const float* __restrict__ sy1,
                      const float* __restrict__ sx2, const float* __restrict__ sy2,
                      const float* __restrict__ ss,
                      const uint64_t* __restrict__ keepw, const int* __restrict__ wpref,
                      float* __restrict__ out, int N) {
  int i = blockIdx.x * blockDim.x + threadIdx.x;
  if (i >= N) return;
  int w = i >> 6, b = i & 63;
  uint64_t kw = keepw[w];
  bool kept = (kw >> b) & 1ull;
  int rank = wpref[w] + __popcll(kw & ((1ull << b) - 1ull));
  bool fin = kept && (rank < MAX_PROPOSALS);

  float* bo = out;
  float* so = out + (size_t)4 * N;
  float* ko = so + N;
  bo[4 * i + 0] = fin ? sx1[i] : 0.0f;
  bo[4 * i + 1] = fin ? sy1[i] : 0.0f;
  bo[4 * i + 2] = fin ? sx2[i] : 0.0f;
  bo[4 * i + 3] = fin ? sy2[i] : 0.0f;
  so[i] = fin ? ss[i] : 0.0f;
  ko[i] = fin ? 1.0f : 0.0f;
}

extern "C" void kernel_launch(void* const* d_in, const int* in_sizes, int n_in,
                              void* d_out, int out_size, void* d_ws, size_t ws_size,
                              hipStream_t stream) {
  const float* boxes  = (const float*)d_in[0];
  const float* scores = (const float*)d_in[1];
  int N = in_sizes[1];
  int W = (N + 63) >> 6;           // 157 for N=10000; layout requires W <= WPAD
  (void)W;

  char* ws = (char*)d_ws;
  size_t off = 0;
  float* sx1 = (float*)(ws + off); off += (size_t)N * 4;
  float* sy1 = (float*)(ws + off); off += (size_t)N * 4;
  float* sx2 = (float*)(ws + off); off += (size_t)N * 4;
  float* sy2 = (float*)(ws + off); off += (size_t)N * 4;
  float* ss  = (float*)(ws + off); off += (size_t)N * 4;
  off = (off + 255) & ~(size_t)255;
  uint64_t* mask = (uint64_t*)(ws + off); off += (size_t)N * WPAD * 8;
  uint64_t* keepw = (uint64_t*)(ws + off); off += (size_t)WPAD * 8;
  int* wpref = (int*)(ws + off); off += (size_t)WPAD * 4;

  int nblk = (N + 255) / 256;
  k_sort<<<nblk, 256, (size_t)N * sizeof(float), stream>>>(boxes, scores, sx1, sy1, sx2, sy2, ss, N);

  dim3 mg(WPAD, (N + 63) / 64);
  k_mask<<<mg, 64, 0, stream>>>(sx1, sy1, sx2, sy2, mask, N);

  k_scan<<<1, 64, 0, stream>>>(mask, keepw, wpref, N);

  k_out<<<nblk, 256, 0, stream>>>(sx1, sy1, sx2, sy2, ss, keepw, wpref, (float*)d_out, N);
}

// Round 2
// 1079.552 us; speedup vs baseline: 4.3278x; 4.3278x over previous
//
#include <hip/hip_runtime.h>
#include <stdint.h>

#define MAX_PROPOSALS 1000
#define WPAD 160   // padded 64-bit words per mask row; layout requires W <= 160

// ---------------------------------------------------------------------------
// K1: stable argsort by descending score via rank counting (unchanged).
// ---------------------------------------------------------------------------
__global__ void k_sort(const float* __restrict__ boxes, const float* __restrict__ scores,
                       float* __restrict__ sx1, float* __restrict__ sy1,
                       float* __restrict__ sx2, float* __restrict__ sy2,
                       float* __restrict__ ss, int N) {
  extern __shared__ float sh[];
  for (int j = threadIdx.x; j < N; j += blockDim.x) sh[j] = scores[j];
  __syncthreads();
  int i = blockIdx.x * blockDim.x + threadIdx.x;
  if (i >= N) return;
  float si = sh[i];
  int rank = 0;
  int j = 0;
  for (; j + 4 <= N; j += 4) {
    float a = sh[j], b = sh[j + 1], c = sh[j + 2], d = sh[j + 3];
    rank += (a > si) || (a == si && (j    ) < i);
    rank += (b > si) || (b == si && (j + 1) < i);
    rank += (c > si) || (c == si && (j + 2) < i);
    rank += (d > si) || (d == si && (j + 3) < i);
  }
  for (; j < N; ++j) {
    float a = sh[j];
    rank += (a > si) || (a == si && j < i);
  }
  sx1[rank] = boxes[4 * i + 0];
  sy1[rank] = boxes[4 * i + 1];
  sx2[rank] = boxes[4 * i + 2];
  sy2[rank] = boxes[4 * i + 3];
  ss[rank]  = si;
}

// ---------------------------------------------------------------------------
// K2: suppression bitmask, UPPER TRIANGLE ONLY (cb >= rb); the scan never
// reads words left of a row's own tile. Exact reference fp32 op sequence.
// ---------------------------------------------------------------------------
__global__ __launch_bounds__(64) void k_mask(const float* __restrict__ sx1, const float* __restrict__ sy1,
                        const float* __restrict__ sx2, const float* __restrict__ sy2,
                        uint64_t* __restrict__ mask, int N) {
  int cb = blockIdx.x;            // column word index
  int rb = blockIdx.y;            // row block
  if (cb < rb) return;            // lower triangle: never read
  int l  = threadIdx.x;           // 0..63
  int row = rb * 64 + l;

  __shared__ float cx1[64], cy1[64], cx2[64], cy2[64], car[64];
  int c = cb * 64 + l;
  if (c < N) {
    float a = sx1[c], b = sy1[c], x = sx2[c], y = sy2[c];
    cx1[l] = a; cy1[l] = b; cx2[l] = x; cy2[l] = y;
    car[l] = (x - a) * (y - b);
  } else {
    cx1[l] = 0.0f; cy1[l] = 0.0f; cx2[l] = 0.0f; cy2[l] = 0.0f; car[l] = 0.0f;
  }
  __syncthreads();

  if (row >= N) return;

  uint64_t bits = 0;
  int cbase = cb * 64;
  if (cbase + 63 > row) {
    float x1 = sx1[row], y1 = sy1[row], x2 = sx2[row], y2 = sy2[row];
    float ar = (x2 - x1) * (y2 - y1);
    for (int jj = 0; jj < 64; ++jj) {
      int j = cbase + jj;
      float ix1 = fmaxf(x1, cx1[jj]);
      float iy1 = fmaxf(y1, cy1[jj]);
      float ix2 = fminf(x2, cx2[jj]);
      float iy2 = fminf(y2, cy2[jj]);
      float iw = fmaxf(ix2 - ix1, 0.0f);
      float ih = fmaxf(iy2 - iy1, 0.0f);
      float inter = iw * ih;
      float uni = ar + car[jj] - inter;
      float iou = inter / fmaxf(uni, 1e-9f);
      if (j > row && j < N && iou > 0.5f) bits |= (1ull << jj);
    }
  }
  mask[(size_t)row * WPAD + cb] = bits;
}

// ---------------------------------------------------------------------------
// K3: tiled block-parallel greedy scan. ONE block, 16 waves.
// Per 64-row tile t:
//   - wave 1 prefetches NEXT tile's diagonal words mask[row][t+1] -> LDS dbuf
//   - lane 0 runs the 64-step in-tile sequential loop on LDS diag (pure ALU,
//     no memory in the dependency chain) -> tile keep word kw
//   - barrier; all 16 waves load ONLY the kept rows' words w>t and atomicOr
//     them into the suppressed-bits accumulator S (LDS) in parallel
//   - barrier; next tile sees updated S[t+1]
// Sequential chain total ~N ALU steps instead of N memory round-trips.
// ---------------------------------------------------------------------------
__global__ __launch_bounds__(1024) void k_scan2(const uint64_t* __restrict__ mask,
                                                uint64_t* __restrict__ keep_out,
                                                int* __restrict__ wpref, int N) {
  const int tid  = threadIdx.x;
  const int lane = tid & 63;
  const int wave = tid >> 6;          // 0..15
  const int nw   = (N + 63) >> 6;     // word count (157)

  __shared__ unsigned int S[2 * WPAD];   // suppressed bits (lo/hi halves)
  __shared__ uint64_t diag[2][64];       // double-buffered diagonal words
  __shared__ uint64_t kwS;               // broadcast of tile keep word
  __shared__ uint64_t keepS[WPAD];       // final keep words

  for (int i = tid; i < 2 * WPAD; i += 1024) S[i] = 0u;
  if (wave == 1) {                       // prefetch diag for tile 0
    int r = lane;
    diag[0][lane] = (r < N) ? mask[(size_t)r * WPAD + 0] : 0ull;
  }
  __syncthreads();

  for (int t = 0; t < nw; ++t) {
    const int buf = t & 1;

    // prefetch next tile's diagonal (latency hidden behind seq loop below)
    if (wave == 1 && t + 1 < nw) {
      int r = (t + 1) * 64 + lane;
      uint64_t v = (r < N) ? mask[(size_t)r * WPAD + (t + 1)] : 0ull;
      diag[buf ^ 1][lane] = v;
    }

    // in-tile sequential greedy loop (single lane, ALU-only chain)
    if (tid == 0) {
      uint64_t s = ((uint64_t)S[2 * t + 1] << 32) | (uint64_t)S[2 * t];
      uint64_t kw = ~s;
      int rem = N - t * 64;
      if (rem < 64) kw &= (rem > 0 ? ((1ull << rem) - 1ull) : 0ull);
      #pragma unroll
      for (int b = 0; b < 64; ++b) {
        uint64_t sel = (uint64_t)(0ll - (int64_t)((kw >> b) & 1ull));
        kw &= ~(diag[buf][b] & sel);
      }
      kwS = kw;
      keepS[t] = kw;
    }
    __syncthreads();

    // parallel suppression: wave v owns rows v, v+16, v+32, v+48 of the tile
    uint64_t kw = kwS;
    #pragma unroll
    for (int q = 0; q < 4; ++q) {
      int b = wave + 16 * q;
      if ((kw >> b) & 1ull) {
        const uint64_t* rp = mask + (size_t)(t * 64 + b) * WPAD;
        for (int w = t + 1 + lane; w < nw; w += 64) {
          uint64_t m = rp[w];
          if (m) {
            atomicOr(&S[2 * w],     (unsigned int)m);
            atomicOr(&S[2 * w + 1], (unsigned int)(m >> 32));
          }
        }
      }
    }
    __syncthreads();
  }

  // epilogue: publish keep words + per-word popcount prefix
  if (tid < WPAD) {
    uint64_t k = (tid < nw) ? keepS[tid] : 0ull;
    keep_out[tid] = k;
  }
  __syncthreads();
  if (tid == 0) {
    int run = 0;
    for (int w = 0; w < WPAD; ++w) {
      wpref[w] = run;
      run += __popcll((w < nw) ? keepS[w] : 0ull);
    }
  }
}

// ---------------------------------------------------------------------------
// K4: ranks via popcount prefix, MAX_PROPOSALS cutoff, write outputs.
// Output layout: boxes (N*4) | scores (N) | keep-as-float (N).
// ---------------------------------------------------------------------------
__global__ void k_out(const float* __restrict__ sx1, const float* __restrict__ sy1,
                      const float* __restrict__ sx2, const float* __restrict__ sy2,
                      const float* __restrict__ ss,
                      const uint64_t* __restrict__ keepw, const int* __restrict__ wpref,
                      float* __restrict__ out, int N) {
  int i = blockIdx.x * blockDim.x + threadIdx.x;
  if (i >= N) return;
  int w = i >> 6, b = i & 63;
  uint64_t kw = keepw[w];
  bool kept = (kw >> b) & 1ull;
  int rank = wpref[w] + __popcll(kw & ((1ull << b) - 1ull));
  bool fin = kept && (rank < MAX_PROPOSALS);

  float* bo = out;
  float* so = out + (size_t)4 * N;
  float* ko = so + N;
  bo[4 * i + 0] = fin ? sx1[i] : 0.0f;
  bo[4 * i + 1] = fin ? sy1[i] : 0.0f;
  bo[4 * i + 2] = fin ? sx2[i] : 0.0f;
  bo[4 * i + 3] = fin ? sy2[i] : 0.0f;
  so[i] = fin ? ss[i] : 0.0f;
  ko[i] = fin ? 1.0f : 0.0f;
}

extern "C" void kernel_launch(void* const* d_in, const int* in_sizes, int n_in,
                              void* d_out, int out_size, void* d_ws, size_t ws_size,
                              hipStream_t stream) {
  const float* boxes  = (const float*)d_in[0];
  const float* scores = (const float*)d_in[1];
  int N = in_sizes[1];
  int W = (N + 63) >> 6;           // 157 for N=10000; layout requires W <= WPAD

  char* ws = (char*)d_ws;
  size_t off = 0;
  float* sx1 = (float*)(ws + off); off += (size_t)N * 4;
  float* sy1 = (float*)(ws + off); off += (size_t)N * 4;
  float* sx2 = (float*)(ws + off); off += (size_t)N * 4;
  float* sy2 = (float*)(ws + off); off += (size_t)N * 4;
  float* ss  = (float*)(ws + off); off += (size_t)N * 4;
  off = (off + 255) & ~(size_t)255;
  uint64_t* mask = (uint64_t*)(ws + off); off += (size_t)N * WPAD * 8;
  uint64_t* keepw = (uint64_t*)(ws + off); off += (size_t)WPAD * 8;
  int* wpref = (int*)(ws + off); off += (size_t)WPAD * 4;

  int nblk = (N + 255) / 256;
  k_sort<<<nblk, 256, (size_t)N * sizeof(float), stream>>>(boxes, scores, sx1, sy1, sx2, sy2, ss, N);

  dim3 mg(W, W);
  k_mask<<<mg, 64, 0, stream>>>(sx1, sy1, sx2, sy2, mask, N);

  k_scan2<<<1, 1024, 0, stream>>>(mask, keepw, wpref, N);

  k_out<<<nblk, 256, 0, stream>>>(sx1, sy1, sx2, sy2, ss, keepw, wpref, (float*)d_out, N);
}

// Round 3
// 535.677 us; speedup vs baseline: 8.7218x; 2.0153x over previous
//
#include <hip/hip_runtime.h>
#include <stdint.h>

#define MAX_PROPOSALS 1000
#define WPAD 160      // static LDS bound on word count; requires W <= 160
#define JCH 8         // j-chunks for the rank phase
#define SUPW 15       // suppression waves in k_scan3
#define MAXT 11       // max word-tasks per suppression wave (15*11 >= 156)

// ---------------------------------------------------------------------------
// K1a: partial rank counts. Block (bi, jc): stages j-chunk scores in LDS,
// counts rank contributions for its 256 i's. rank2d[jc][i], no atomics.
// ---------------------------------------------------------------------------
__global__ __launch_bounds__(256) void k_rank(const float* __restrict__ scores,
                                              int* __restrict__ rank2d, int N) {
  int jc = blockIdx.y;
  int chunk = (N + JCH - 1) / JCH;
  int j0 = jc * chunk;
  int j1 = min(N, j0 + chunk);
  extern __shared__ float sh[];
  for (int j = j0 + threadIdx.x; j < j1; j += 256) sh[j - j0] = scores[j];
  __syncthreads();
  int i = blockIdx.x * 256 + threadIdx.x;
  if (i >= N) return;
  float si = scores[i];
  int r = 0;
  int j = j0;
  for (; j + 4 <= j1; j += 4) {
    float a = sh[j - j0], b = sh[j - j0 + 1], c = sh[j - j0 + 2], d = sh[j - j0 + 3];
    r += (a > si) || (a == si && (j    ) < i);
    r += (b > si) || (b == si && (j + 1) < i);
    r += (c > si) || (c == si && (j + 2) < i);
    r += (d > si) || (d == si && (j + 3) < i);
  }
  for (; j < j1; ++j) {
    float a = sh[j - j0];
    r += (a > si) || (a == si && j < i);
  }
  rank2d[(size_t)jc * N + i] = r;
}

// K1b: sum partial ranks, scatter boxes/scores into sorted SoA.
__global__ __launch_bounds__(256) void k_scatter(const float* __restrict__ boxes,
                       const float* __restrict__ scores, const int* __restrict__ rank2d,
                       float* __restrict__ sx1, float* __restrict__ sy1,
                       float* __restrict__ sx2, float* __restrict__ sy2,
                       float* __restrict__ ss, int N) {
  int i = blockIdx.x * 256 + threadIdx.x;
  if (i >= N) return;
  int r = 0;
  #pragma unroll
  for (int c = 0; c < JCH; ++c) r += rank2d[(size_t)c * N + i];
  sx1[r] = boxes[4 * i + 0];
  sy1[r] = boxes[4 * i + 1];
  sx2[r] = boxes[4 * i + 2];
  sy2[r] = boxes[4 * i + 3];
  ss[r]  = scores[i];
}

// ---------------------------------------------------------------------------
// K2: suppression bitmask, TRANSPOSED layout maskT[word][row] (coalesced
// column reads for the scan). Block = 4 waves; wave wv handles tile
// (rb, cb = 4*bx+wv), upper triangle only. Lane = column; rows broadcast via
// readlane; word assembled via __ballot. Exact reference fp32 op sequence
// (separate max/min/sub/mul, (rowArea+colArea)-inter, IEEE divide).
// ---------------------------------------------------------------------------
__global__ __launch_bounds__(256) void k_mask(const float* __restrict__ sx1, const float* __restrict__ sy1,
                        const float* __restrict__ sx2, const float* __restrict__ sy2,
                        uint64_t* __restrict__ maskT, int NP, int N, int W) {
  int wv = threadIdx.x >> 6, lane = threadIdx.x & 63;
  int rb = blockIdx.y;
  int cb = blockIdx.x * 4 + wv;
  if (cb < rb || cb >= W) return;

  int row = rb * 64 + lane;          // this lane's ROW (for data + final store)
  int c   = cb * 64 + lane;          // this lane's COLUMN (IoU lane)
  int rl = min(row, N - 1), cl = min(c, N - 1);
  float rx1 = sx1[rl], ry1 = sy1[rl], rx2 = sx2[rl], ry2 = sy2[rl];
  float rar = (rx2 - rx1) * (ry2 - ry1);
  float cx1 = sx1[cl], cy1 = sy1[cl], cx2 = sx2[cl], cy2 = sy2[cl];
  float car = (cx2 - cx1) * (cy2 - cy1);

  uint64_t myw = 0;
  #pragma unroll 8
  for (int i = 0; i < 64; ++i) {
    float x1 = __int_as_float(__builtin_amdgcn_readlane(__float_as_int(rx1), i));
    float y1 = __int_as_float(__builtin_amdgcn_readlane(__float_as_int(ry1), i));
    float x2 = __int_as_float(__builtin_amdgcn_readlane(__float_as_int(rx2), i));
    float y2 = __int_as_float(__builtin_amdgcn_readlane(__float_as_int(ry2), i));
    float ar = __int_as_float(__builtin_amdgcn_readlane(__float_as_int(rar), i));
    float ix1 = fmaxf(x1, cx1);
    float iy1 = fmaxf(y1, cy1);
    float ix2 = fminf(x2, cx2);
    float iy2 = fminf(y2, cy2);
    float iw = fmaxf(ix2 - ix1, 0.0f);
    float ih = fmaxf(iy2 - iy1, 0.0f);
    float inter = iw * ih;
    float uni = (ar + car) - inter;
    float iou = inter / fmaxf(uni, 1e-9f);
    int rowi = rb * 64 + i;
    bool pred = (iou > 0.5f) && (c > rowi) && (c < N);
    uint64_t ball = __ballot(pred);
    if (lane == i) myw = ball;
  }
  maskT[(size_t)cb * NP + row] = myw;
}

// ---------------------------------------------------------------------------
// K3: tiled greedy scan, ONE block, 16 waves, transposed mask.
// Per tile t:
//  - wave 0: prefetch next diag (regs), run 64-step scalar-chain greedy loop
//    (readlane + 64-bit scalar ops, no memory in the chain) -> kwS
//  - waves 1..15: MEANWHILE issue their suppression-word loads
//    m = maskT[w][64t+lane] (independent of kw -> latency overlaps seq loop)
//  - barrier; waves 1..15 apply: mm = kept(lane) ? m : 0; sparse LDS atomicOr
//  - barrier; S[t+1] final for next tile.
// ---------------------------------------------------------------------------
__global__ __launch_bounds__(1024) void k_scan3(const uint64_t* __restrict__ maskT, int NP,
                                                uint64_t* __restrict__ keep_out,
                                                int* __restrict__ wpref, int N) {
  const int tid = threadIdx.x, lane = tid & 63, wave = tid >> 6;
  const int nw = (N + 63) >> 6;

  __shared__ unsigned int S[2 * WPAD];   // suppressed bits (lo/hi)
  __shared__ unsigned int kwS[2];        // broadcast tile keep word
  __shared__ uint64_t keepS[WPAD];

  for (int i = tid; i < 2 * WPAD; i += 1024) S[i] = 0u;
  __syncthreads();

  uint64_t dw = 0;
  if (wave == 0) dw = maskT[lane];       // diag words of tile 0

  for (int t = 0; t < nw; ++t) {
    // entry invariant: S[t] final
    if (wave == 0) {
      // prefetch next tile's diag FIRST (overlaps the sequential loop)
      uint64_t dwn = 0;
      if (t + 1 < nw) dwn = maskT[(size_t)(t + 1) * NP + (t + 1) * 64 + lane];

      uint64_t s = ((uint64_t)S[2 * t + 1] << 32) | (uint64_t)S[2 * t];
      uint64_t kw = ~s;
      int rem = N - t * 64;
      if (rem < 64) kw &= ((1ull << rem) - 1ull);
      unsigned int dlo = (unsigned int)dw, dhi = (unsigned int)(dw >> 32);
      #pragma unroll
      for (int b = 0; b < 64; ++b) {
        unsigned int lo = (unsigned int)__builtin_amdgcn_readlane((int)dlo, b);
        unsigned int hi = (unsigned int)__builtin_amdgcn_readlane((int)dhi, b);
        uint64_t dwb = ((uint64_t)hi << 32) | (uint64_t)lo;
        uint64_t bit = (kw >> b) & 1ull;
        kw &= ~(dwb & (0ull - bit));
      }
      if (lane == 0) {
        kwS[0] = (unsigned int)kw;
        kwS[1] = (unsigned int)(kw >> 32);
        keepS[t] = kw;
      }
      dw = dwn;
      __syncthreads();                    // A: kwS visible, m-loads drained
      __syncthreads();                    // B: applies done
    } else {
      int wv = wave - 1;
      uint64_t mr[MAXT];
      #pragma unroll
      for (int k = 0; k < MAXT; ++k) {
        int w = t + 1 + wv + SUPW * k;
        mr[k] = (w < nw) ? maskT[(size_t)w * NP + t * 64 + lane] : 0ull;
      }
      __syncthreads();                    // A: kwS ready
      uint64_t kw = ((uint64_t)kwS[1] << 32) | (uint64_t)kwS[0];
      uint64_t sel = 0ull - ((kw >> lane) & 1ull);
      #pragma unroll
      for (int k = 0; k < MAXT; ++k) {
        int w = t + 1 + wv + SUPW * k;
        uint64_t mm = mr[k] & sel;
        if (w < nw && mm) {
          unsigned int lo = (unsigned int)mm, hi = (unsigned int)(mm >> 32);
          if (lo) atomicOr(&S[2 * w], lo);
          if (hi) atomicOr(&S[2 * w + 1], hi);
        }
      }
      __syncthreads();                    // B: applies done
    }
  }

  // epilogue: publish keep words + per-word popcount prefix
  if (tid < WPAD) keep_out[tid] = (tid < nw) ? keepS[tid] : 0ull;
  if (tid == 0) {
    int run = 0;
    for (int w = 0; w < WPAD; ++w) {
      wpref[w] = run;
      run += __popcll((w < nw) ? keepS[w] : 0ull);
    }
  }
}

// ---------------------------------------------------------------------------
// K4: ranks via popcount prefix, MAX_PROPOSALS cutoff, write outputs.
// Output layout: boxes (N*4) | scores (N) | keep-as-float (N).
// ---------------------------------------------------------------------------
__global__ __launch_bounds__(256) void k_out(const float* __restrict__ sx1, const float* __restrict__ sy1,
                      const float* __restrict__ sx2, const float* __restrict__ sy2,
                      const float* __restrict__ ss,
                      const uint64_t* __restrict__ keepw, const int* __restrict__ wpref,
                      float* __restrict__ out, int N) {
  int i = blockIdx.x * blockDim.x + threadIdx.x;
  if (i >= N) return;
  int w = i >> 6, b = i & 63;
  uint64_t kw = keepw[w];
  bool kept = (kw >> b) & 1ull;
  int rank = wpref[w] + __popcll(kw & ((1ull << b) - 1ull));
  bool fin = kept && (rank < MAX_PROPOSALS);

  float* bo = out;
  float* so = out + (size_t)4 * N;
  float* ko = so + N;
  bo[4 * i + 0] = fin ? sx1[i] : 0.0f;
  bo[4 * i + 1] = fin ? sy1[i] : 0.0f;
  bo[4 * i + 2] = fin ? sx2[i] : 0.0f;
  bo[4 * i + 3] = fin ? sy2[i] : 0.0f;
  so[i] = fin ? ss[i] : 0.0f;
  ko[i] = fin ? 1.0f : 0.0f;
}

extern "C" void kernel_launch(void* const* d_in, const int* in_sizes, int n_in,
                              void* d_out, int out_size, void* d_ws, size_t ws_size,
                              hipStream_t stream) {
  const float* boxes  = (const float*)d_in[0];
  const float* scores = (const float*)d_in[1];
  int N = in_sizes[1];
  int W = (N + 63) >> 6;            // 157 for N=10000; layout requires W <= WPAD
  int NP = W * 64;                  // padded row count per mask column

  char* ws = (char*)d_ws;
  size_t off = 0;
  float* sx1 = (float*)(ws + off); off += (size_t)N * 4;
  float* sy1 = (float*)(ws + off); off += (size_t)N * 4;
  float* sx2 = (float*)(ws + off); off += (size_t)N * 4;
  float* sy2 = (float*)(ws + off); off += (size_t)N * 4;
  float* ss  = (float*)(ws + off); off += (size_t)N * 4;
  off = (off + 255) & ~(size_t)255;
  int* rank2d = (int*)(ws + off); off += (size_t)JCH * N * 4;
  off = (off + 255) & ~(size_t)255;
  uint64_t* maskT = (uint64_t*)(ws + off); off += (size_t)W * NP * 8;
  uint64_t* keepw = (uint64_t*)(ws + off); off += (size_t)WPAD * 8;
  int* wpref = (int*)(ws + off); off += (size_t)WPAD * 4;

  int nblk = (N + 255) / 256;
  int chunk = (N + JCH - 1) / JCH;

  k_rank<<<dim3(nblk, JCH), 256, (size_t)chunk * sizeof(float), stream>>>(scores, rank2d, N);
  k_scatter<<<nblk, 256, 0, stream>>>(boxes, scores, rank2d, sx1, sy1, sx2, sy2, ss, N);

  dim3 mg((W + 3) / 4, W);
  k_mask<<<mg, 256, 0, stream>>>(sx1, sy1, sx2, sy2, maskT, NP, N, W);

  k_scan3<<<1, 1024, 0, stream>>>(maskT, NP, keepw, wpref, N);

  k_out<<<nblk, 256, 0, stream>>>(sx1, sy1, sx2, sy2, ss, keepw, wpref, (float*)d_out, N);
}

// Round 4
// 238.920 us; speedup vs baseline: 19.5549x; 2.2421x over previous
//
#include <hip/hip_runtime.h>
#include <stdint.h>

#define MAX_PROPOSALS 1000
#define WPAD 160      // static bound on 64-bit word count; requires W <= 160
#define JCH 8         // j-chunks for the rank phase
#define CAP 2048      // per-tile edge capacity (expected ~100, Poisson, huge margin)

__device__ __forceinline__ uint64_t shfl_u64(uint64_t v, int lane) {
  int lo = __shfl((int)(unsigned int)v, lane, 64);
  int hi = __shfl((int)(unsigned int)(v >> 32), lane, 64);
  return ((uint64_t)(unsigned int)hi << 32) | (uint64_t)(unsigned int)lo;
}

// ---------------------------------------------------------------------------
// K1a: partial rank counts (stable argsort by descending score).
// Also zero-inits tcnt (tile edge cursors) since d_ws is re-poisoned per call.
// ---------------------------------------------------------------------------
__global__ __launch_bounds__(256) void k_rank(const float* __restrict__ scores,
                                              int* __restrict__ rank2d,
                                              int* __restrict__ tcnt, int N) {
  if (blockIdx.x == 0 && blockIdx.y == 0 && threadIdx.x < WPAD) tcnt[threadIdx.x] = 0;
  int jc = blockIdx.y;
  int chunk = (N + JCH - 1) / JCH;
  int j0 = jc * chunk;
  int j1 = min(N, j0 + chunk);
  extern __shared__ float sh[];
  for (int j = j0 + threadIdx.x; j < j1; j += 256) sh[j - j0] = scores[j];
  __syncthreads();
  int i = blockIdx.x * 256 + threadIdx.x;
  if (i >= N) return;
  float si = scores[i];
  int r = 0;
  int j = j0;
  for (; j + 4 <= j1; j += 4) {
    float a = sh[j - j0], b = sh[j - j0 + 1], c = sh[j - j0 + 2], d = sh[j - j0 + 3];
    r += (a > si) || (a == si && (j    ) < i);
    r += (b > si) || (b == si && (j + 1) < i);
    r += (c > si) || (c == si && (j + 2) < i);
    r += (d > si) || (d == si && (j + 3) < i);
  }
  for (; j < j1; ++j) {
    float a = sh[j - j0];
    r += (a > si) || (a == si && j < i);
  }
  rank2d[(size_t)jc * N + i] = r;
}

// K1b: sum partial ranks, scatter boxes/scores into sorted SoA.
__global__ __launch_bounds__(256) void k_scatter(const float* __restrict__ boxes,
                       const float* __restrict__ scores, const int* __restrict__ rank2d,
                       float* __restrict__ sx1, float* __restrict__ sy1,
                       float* __restrict__ sx2, float* __restrict__ sy2,
                       float* __restrict__ ss, int N) {
  int i = blockIdx.x * 256 + threadIdx.x;
  if (i >= N) return;
  int r = 0;
  #pragma unroll
  for (int c = 0; c < JCH; ++c) r += rank2d[(size_t)c * N + i];
  sx1[r] = boxes[4 * i + 0];
  sy1[r] = boxes[4 * i + 1];
  sx2[r] = boxes[4 * i + 2];
  sy2[r] = boxes[4 * i + 3];
  ss[r]  = scores[i];
}

// ---------------------------------------------------------------------------
// K2: sparse suppression graph. Wave per upper-triangle tile-pair (rb,cb).
// Lane = column; rows broadcast via readlane; per-row word via __ballot.
// rb==cb -> diagArr[rb*64+lane]; rb<cb -> packed edges (rowbit<<16|col)
// appended to per-tile list via atomicAdd cursor.
// IoU decision: inter > 0.5*m (EXACT: 0.5*m is exact; true division fallback
// in the one-ulp ambiguity window so decisions match the reference bitwise).
// ---------------------------------------------------------------------------
__global__ __launch_bounds__(256) void k_mask2(const float* __restrict__ sx1, const float* __restrict__ sy1,
                        const float* __restrict__ sx2, const float* __restrict__ sy2,
                        uint64_t* __restrict__ diagArr, uint32_t* __restrict__ edgebuf,
                        int* __restrict__ tcnt, int N, int W) {
  int wv = threadIdx.x >> 6, lane = threadIdx.x & 63;
  int rb = blockIdx.y;
  int cb = blockIdx.x * 4 + wv;
  if (cb < rb || cb >= W) return;

  int row = rb * 64 + lane;          // this lane's ROW (data + final word owner)
  int c   = cb * 64 + lane;          // this lane's COLUMN (IoU lane)
  int rl = min(row, N - 1), cl = min(c, N - 1);
  float rx1 = sx1[rl], ry1 = sy1[rl], rx2 = sx2[rl], ry2 = sy2[rl];
  float rar = (rx2 - rx1) * (ry2 - ry1);
  float cx1 = sx1[cl], cy1 = sy1[cl], cx2 = sx2[cl], cy2 = sy2[cl];
  float car = (cx2 - cx1) * (cy2 - cy1);

  uint64_t myw = 0;
  #pragma unroll 8
  for (int i = 0; i < 64; ++i) {
    float x1 = __int_as_float(__builtin_amdgcn_readlane(__float_as_int(rx1), i));
    float y1 = __int_as_float(__builtin_amdgcn_readlane(__float_as_int(ry1), i));
    float x2 = __int_as_float(__builtin_amdgcn_readlane(__float_as_int(rx2), i));
    float y2 = __int_as_float(__builtin_amdgcn_readlane(__float_as_int(ry2), i));
    float ar = __int_as_float(__builtin_amdgcn_readlane(__float_as_int(rar), i));
    float ix1 = fmaxf(x1, cx1);
    float iy1 = fmaxf(y1, cy1);
    float ix2 = fminf(x2, cx2);
    float iy2 = fminf(y2, cy2);
    float iw = fmaxf(ix2 - ix1, 0.0f);
    float ih = fmaxf(iy2 - iy1, 0.0f);
    float inter = iw * ih;
    float uni = (ar + car) - inter;
    float m_ = fmaxf(uni, 1e-9f);
    float t_ = 0.5f * m_;                 // exact (scale by power of two)
    bool pred = inter > t_;               // == (inter/m_ > 0.5) except 1-ulp window
    if (pred && inter <= t_ + t_ * 3e-7f) // ambiguity window: use exact reference op
      pred = (inter / m_) > 0.5f;
    int rowi = rb * 64 + i;
    bool bit = pred && (c > rowi) && (c < N);
    uint64_t ball = __ballot(bit);
    if (lane == i) myw = ball;
  }

  if (rb == cb) {
    diagArr[(size_t)rb * 64 + lane] = myw;     // includes in-tile j>i bits
  } else if (row < N) {
    uint64_t w = myw;
    while (w) {
      int jj = __builtin_ctzll(w);
      w &= w - 1;
      int pos = atomicAdd(&tcnt[rb], 1);
      if (pos < CAP) edgebuf[(size_t)rb * CAP + pos] = ((uint32_t)lane << 16) | (uint32_t)(cb * 64 + jj);
    }
  }
}

// ---------------------------------------------------------------------------
// K3: single-wave barrier-free greedy scan over the sparse graph.
// Per tile t: read S[t] (LDS) -> sparse in-tile chain (ballot over nonzero
// diag words, ~0-2 iters typical) -> kw; apply tile t's edges (prefetched
// last iteration) predicated on kw via LDS atomicOr into future S words.
// Tile t+1's diag/count/edges prefetched at the top (latency overlapped).
// ---------------------------------------------------------------------------
__global__ __launch_bounds__(64) void k_scan5(const uint64_t* __restrict__ diagArr,
                                              const uint32_t* __restrict__ edgebuf,
                                              const int* __restrict__ tcnt,
                                              uint64_t* __restrict__ keep_out,
                                              int* __restrict__ wpref, int N) {
  const int l = threadIdx.x;
  const int nw = (N + 63) >> 6;

  __shared__ uint32_t S[2 * WPAD];
  __shared__ uint64_t keepL[WPAD];
  for (int i = l; i < 2 * WPAD; i += 64) S[i] = 0u;
  for (int i = l; i < WPAD; i += 64) keepL[i] = 0ull;
  __syncthreads();

  // prefetch tile 0
  uint64_t dw = diagArr[l];
  int cn = tcnt[0];
  uint32_t e0 = edgebuf[l], e1 = edgebuf[64 + l], e2 = edgebuf[128 + l], e3 = edgebuf[192 + l];

  for (int t = 0; t < nw; ++t) {
    // issue S[t] read first (latency overlaps prefetch issue below)
    uint32_t slo = S[2 * t], shi = S[2 * t + 1];

    // prefetch tile t+1 (independent of kw)
    uint64_t dwn = 0; int cnn = 0;
    uint32_t f0 = 0, f1 = 0, f2 = 0, f3 = 0;
    if (t + 1 < nw) {
      dwn = diagArr[(size_t)(t + 1) * 64 + l];
      cnn = tcnt[t + 1];
      const uint32_t* eb = edgebuf + (size_t)(t + 1) * CAP;
      f0 = eb[l]; f1 = eb[64 + l]; f2 = eb[128 + l]; f3 = eb[192 + l];
    }

    uint64_t kw = ~(((uint64_t)shi << 32) | (uint64_t)slo);
    int rem = N - t * 64;
    if (rem < 64) kw &= ((1ull << rem) - 1ull);

    uint64_t m = __ballot(dw != 0ull);       // sparse: ~0-2 bits typical
    while (m) {
      int b = __builtin_ctzll(m);
      m &= m - 1;
      if ((kw >> b) & 1ull) kw &= ~shfl_u64(dw, b);
    }
    if (l == 0) keepL[t] = kw;

    // apply this tile's edges, predicated on final kw
    int c = min(cn, CAP);
    uint32_t ee[4] = {e0, e1, e2, e3};
    #pragma unroll
    for (int k = 0; k < 4; ++k) {
      int idx = 64 * k + l;
      if (idx < c) {
        int b = (int)(ee[k] >> 16), j = (int)(ee[k] & 0xFFFFu);
        if ((kw >> b) & 1ull)
          atomicOr(&S[2 * (j >> 6) + ((j >> 5) & 1)], 1u << (j & 31));
      }
    }
    if (c > 256) {                           // overflow path (expected never)
      const uint32_t* eb = edgebuf + (size_t)t * CAP;
      for (int k = 256 + l; k < c; k += 64) {
        uint32_t e = eb[k];
        int b = (int)(e >> 16), j = (int)(e & 0xFFFFu);
        if ((kw >> b) & 1ull)
          atomicOr(&S[2 * (j >> 6) + ((j >> 5) & 1)], 1u << (j & 31));
      }
    }
    __threadfence_block();                   // order atomicOr before next S read

    dw = dwn; cn = cnn; e0 = f0; e1 = f1; e2 = f2; e3 = f3;
  }

  __syncthreads();
  // publish keep words (coalesced) + exclusive popcount prefix via wave scans
  uint64_t k0 = keepL[l], k1 = keepL[64 + l], k2 = (l < WPAD - 128) ? keepL[128 + l] : 0ull;
  keep_out[l] = k0;
  keep_out[64 + l] = k1;
  if (l < WPAD - 128) keep_out[128 + l] = k2;

  int p0 = __popcll(k0), p1 = __popcll(k1), p2 = __popcll(k2);
  int s0 = p0, s1 = p1, s2 = p2;
  #pragma unroll
  for (int d = 1; d < 64; d <<= 1) {
    int v0 = __shfl_up(s0, d, 64), v1 = __shfl_up(s1, d, 64), v2 = __shfl_up(s2, d, 64);
    if (l >= d) { s0 += v0; s1 += v1; s2 += v2; }
  }
  int tot0 = __shfl(s0, 63, 64);
  int tot1 = __shfl(s1, 63, 64);
  wpref[l] = s0 - p0;
  wpref[64 + l] = tot0 + s1 - p1;
  if (l < WPAD - 128) wpref[128 + l] = tot0 + tot1 + s2 - p2;
}

// ---------------------------------------------------------------------------
// K4: ranks via popcount prefix, MAX_PROPOSALS cutoff, write outputs.
// Output layout: boxes (N*4) | scores (N) | keep-as-float (N).
// ---------------------------------------------------------------------------
__global__ __launch_bounds__(256) void k_out(const float* __restrict__ sx1, const float* __restrict__ sy1,
                      const float* __restrict__ sx2, const float* __restrict__ sy2,
                      const float* __restrict__ ss,
                      const uint64_t* __restrict__ keepw, const int* __restrict__ wpref,
                      float* __restrict__ out, int N) {
  int i = blockIdx.x * blockDim.x + threadIdx.x;
  if (i >= N) return;
  int w = i >> 6, b = i & 63;
  uint64_t kw = keepw[w];
  bool kept = (kw >> b) & 1ull;
  int rank = wpref[w] + __popcll(kw & ((1ull << b) - 1ull));
  bool fin = kept && (rank < MAX_PROPOSALS);

  float* bo = out;
  float* so = out + (size_t)4 * N;
  float* ko = so + N;
  bo[4 * i + 0] = fin ? sx1[i] : 0.0f;
  bo[4 * i + 1] = fin ? sy1[i] : 0.0f;
  bo[4 * i + 2] = fin ? sx2[i] : 0.0f;
  bo[4 * i + 3] = fin ? sy2[i] : 0.0f;
  so[i] = fin ? ss[i] : 0.0f;
  ko[i] = fin ? 1.0f : 0.0f;
}

extern "C" void kernel_launch(void* const* d_in, const int* in_sizes, int n_in,
                              void* d_out, int out_size, void* d_ws, size_t ws_size,
                              hipStream_t stream) {
  const float* boxes  = (const float*)d_in[0];
  const float* scores = (const float*)d_in[1];
  int N = in_sizes[1];
  int W = (N + 63) >> 6;            // 157 for N=10000; layout requires W <= WPAD

  char* ws = (char*)d_ws;
  size_t off = 0;
  float* sx1 = (float*)(ws + off); off += (size_t)N * 4;
  float* sy1 = (float*)(ws + off); off += (size_t)N * 4;
  float* sx2 = (float*)(ws + off); off += (size_t)N * 4;
  float* sy2 = (float*)(ws + off); off += (size_t)N * 4;
  float* ss  = (float*)(ws + off); off += (size_t)N * 4;
  off = (off + 255) & ~(size_t)255;
  int* rank2d = (int*)(ws + off); off += (size_t)JCH * N * 4;
  off = (off + 255) & ~(size_t)255;
  uint64_t* diagArr = (uint64_t*)(ws + off); off += (size_t)WPAD * 64 * 8;
  uint32_t* edgebuf = (uint32_t*)(ws + off); off += (size_t)WPAD * CAP * 4;
  int* tcnt = (int*)(ws + off); off += (size_t)WPAD * 4;
  off = (off + 255) & ~(size_t)255;
  uint64_t* keepw = (uint64_t*)(ws + off); off += (size_t)WPAD * 8;
  int* wpref = (int*)(ws + off); off += (size_t)WPAD * 4;

  int nblk = (N + 255) / 256;
  int chunk = (N + JCH - 1) / JCH;

  k_rank<<<dim3(nblk, JCH), 256, (size_t)chunk * sizeof(float), stream>>>(scores, rank2d, tcnt, N);
  k_scatter<<<nblk, 256, 0, stream>>>(boxes, scores, rank2d, sx1, sy1, sx2, sy2, ss, N);

  dim3 mg((W + 3) / 4, W);
  k_mask2<<<mg, 256, 0, stream>>>(sx1, sy1, sx2, sy2, diagArr, edgebuf, tcnt, N, W);

  k_scan5<<<1, 64, 0, stream>>>(diagArr, edgebuf, tcnt, keepw, wpref, N);

  k_out<<<nblk, 256, 0, stream>>>(sx1, sy1, sx2, sy2, ss, keepw, wpref, (float*)d_out, N);
}

// Round 5
// 223.148 us; speedup vs baseline: 20.9370x; 1.0707x over previous
//
#include <hip/hip_runtime.h>
#include <stdint.h>

#define MAX_PROPOSALS 1000
#define WPAD 160      // static bound on 64-bit word count; requires W <= 160
#define JCH 16        // j-chunks for the rank phase
#define CAP 2048      // per-tile edge capacity (expected ~100, huge margin)

__device__ __forceinline__ uint64_t shfl_u64(uint64_t v, int lane) {
  int lo = __shfl((int)(unsigned int)v, lane, 64);
  int hi = __shfl((int)(unsigned int)(v >> 32), lane, 64);
  return ((uint64_t)(unsigned int)hi << 32) | (uint64_t)(unsigned int)lo;
}

// ---------------------------------------------------------------------------
// K1a: partial rank counts (stable argsort by descending score).
// Also zero-inits tcnt (tile edge cursors) since d_ws is re-poisoned per call.
// ---------------------------------------------------------------------------
__global__ __launch_bounds__(256) void k_rank(const float* __restrict__ scores,
                                              int* __restrict__ rank2d,
                                              int* __restrict__ tcnt, int N) {
  if (blockIdx.x == 0 && blockIdx.y == 0 && threadIdx.x < WPAD) tcnt[threadIdx.x] = 0;
  int jc = blockIdx.y;
  int chunk = (N + JCH - 1) / JCH;
  int j0 = jc * chunk;
  int j1 = min(N, j0 + chunk);
  extern __shared__ float sh[];
  for (int j = j0 + threadIdx.x; j < j1; j += 256) sh[j - j0] = scores[j];
  __syncthreads();
  int i = blockIdx.x * 256 + threadIdx.x;
  if (i >= N) return;
  float si = scores[i];
  int r = 0;
  int j = j0;
  for (; j + 4 <= j1; j += 4) {
    float a = sh[j - j0], b = sh[j - j0 + 1], c = sh[j - j0 + 2], d = sh[j - j0 + 3];
    r += (a > si) || (a == si && (j    ) < i);
    r += (b > si) || (b == si && (j + 1) < i);
    r += (c > si) || (c == si && (j + 2) < i);
    r += (d > si) || (d == si && (j + 3) < i);
  }
  for (; j < j1; ++j) {
    float a = sh[j - j0];
    r += (a > si) || (a == si && j < i);
  }
  rank2d[(size_t)jc * N + i] = r;
}

// K1b: sum partial ranks, scatter boxes (as float4) + scores into sorted order.
__global__ __launch_bounds__(256) void k_scatter(const float4* __restrict__ boxes,
                       const float* __restrict__ scores, const int* __restrict__ rank2d,
                       float4* __restrict__ sbox, float* __restrict__ ss, int N) {
  int i = blockIdx.x * 256 + threadIdx.x;
  if (i >= N) return;
  int r = 0;
  #pragma unroll
  for (int c = 0; c < JCH; ++c) r += rank2d[(size_t)c * N + i];
  sbox[r] = boxes[i];
  ss[r]   = scores[i];
}

// ---------------------------------------------------------------------------
// K2: sparse suppression graph. Wave per upper-triangle tile-pair (rb,cb).
// Lane = column; rows broadcast via readlane; per-row word via __ballot.
// rb==cb -> diagArr[rb*64+lane]; rb<cb -> packed edges (rowbit<<16|col)
// appended to per-tile list via atomicAdd cursor.
// IoU decision: inter > 0.5*m (0.5*m exact; true-division fallback in the
// one-ulp ambiguity window so decisions match the reference bitwise).
// ---------------------------------------------------------------------------
__global__ __launch_bounds__(256) void k_mask2(const float4* __restrict__ sbox,
                        uint64_t* __restrict__ diagArr, uint32_t* __restrict__ edgebuf,
                        int* __restrict__ tcnt, int N, int W) {
  int wv = threadIdx.x >> 6, lane = threadIdx.x & 63;
  int rb = blockIdx.y;
  int cb = blockIdx.x * 4 + wv;
  if (cb < rb || cb >= W) return;

  int row = rb * 64 + lane;          // this lane's ROW (data + final word owner)
  int c   = cb * 64 + lane;          // this lane's COLUMN (IoU lane)
  int rl = min(row, N - 1), cl = min(c, N - 1);
  float4 rB = sbox[rl];
  float rar = (rB.z - rB.x) * (rB.w - rB.y);
  float4 cB = sbox[cl];
  float car = (cB.z - cB.x) * (cB.w - cB.y);

  uint64_t myw = 0;
  #pragma unroll 8
  for (int i = 0; i < 64; ++i) {
    float x1 = __int_as_float(__builtin_amdgcn_readlane(__float_as_int(rB.x), i));
    float y1 = __int_as_float(__builtin_amdgcn_readlane(__float_as_int(rB.y), i));
    float x2 = __int_as_float(__builtin_amdgcn_readlane(__float_as_int(rB.z), i));
    float y2 = __int_as_float(__builtin_amdgcn_readlane(__float_as_int(rB.w), i));
    float ar = __int_as_float(__builtin_amdgcn_readlane(__float_as_int(rar), i));
    float ix1 = fmaxf(x1, cB.x);
    float iy1 = fmaxf(y1, cB.y);
    float ix2 = fminf(x2, cB.z);
    float iy2 = fminf(y2, cB.w);
    float iw = fmaxf(ix2 - ix1, 0.0f);
    float ih = fmaxf(iy2 - iy1, 0.0f);
    float inter = iw * ih;
    float uni = (ar + car) - inter;
    float m_ = fmaxf(uni, 1e-9f);
    float t_ = 0.5f * m_;                 // exact (scale by power of two)
    bool pred = inter > t_;               // == (inter/m_ > 0.5) except 1-ulp window
    if (pred && inter <= t_ + t_ * 3e-7f) // ambiguity window: exact reference op
      pred = (inter / m_) > 0.5f;
    int rowi = rb * 64 + i;
    bool bit = pred && (c > rowi) && (c < N);
    uint64_t ball = __ballot(bit);
    if (lane == i) myw = ball;
  }

  if (rb == cb) {
    diagArr[(size_t)rb * 64 + lane] = myw;     // includes in-tile j>i bits
  } else if (row < N) {
    uint64_t w = myw;
    while (w) {
      int jj = __builtin_ctzll(w);
      w &= w - 1;
      int pos = atomicAdd(&tcnt[rb], 1);
      if (pos < CAP) edgebuf[(size_t)rb * CAP + pos] = ((uint32_t)lane << 16) | (uint32_t)(cb * 64 + jj);
    }
  }
}

// ---------------------------------------------------------------------------
// K3: scan + output, ONE block of 1024. Wave 0 runs the barrier-free greedy
// scan over the sparse graph with:
//   - lgkm-ONLY fence (asm s_waitcnt lgkmcnt(0)) so global prefetch loads
//     (vmcnt) stay in flight across the per-tile ordering point
//   - depth-2 prefetch of diag/edges (global) and counts (LDS-staged tcnt)
//   - S[t+1] read right after the fence (final: all sources <= t applied)
// Then one __syncthreads and all 16 waves write the outputs from LDS keep
// words (merges the old k_out launch).
// ---------------------------------------------------------------------------
__global__ __launch_bounds__(1024) void k_scan6(const uint64_t* __restrict__ diagArr,
                                                const uint32_t* __restrict__ edgebuf,
                                                const int* __restrict__ tcnt,
                                                const float4* __restrict__ sbox,
                                                const float* __restrict__ ss,
                                                float* __restrict__ out, int N) {
  const int tid = threadIdx.x, l = tid & 63, wave = tid >> 6;
  const int nw = (N + 63) >> 6;

  __shared__ uint32_t S[2 * WPAD];
  __shared__ uint64_t keepL[WPAD];
  __shared__ int cntL[WPAD];
  __shared__ int wprefL[WPAD];

  for (int i = tid; i < 2 * WPAD; i += 1024) S[i] = 0u;
  for (int i = tid; i < WPAD; i += 1024) cntL[i] = (i < nw) ? tcnt[i] : 0;
  __syncthreads();

  if (wave == 0) {
    // prefetch tiles 0 and 1 into registers (vmcnt-tracked, never fenced)
    uint64_t dw0 = diagArr[l];
    uint32_t a0 = edgebuf[l], a1 = edgebuf[64 + l], a2 = edgebuf[128 + l], a3 = edgebuf[192 + l];
    uint64_t dw1 = 0;
    uint32_t b0 = 0, b1 = 0, b2 = 0, b3 = 0;
    if (nw > 1) {
      dw1 = diagArr[64 + l];
      const uint32_t* eb = edgebuf + CAP;
      b0 = eb[l]; b1 = eb[64 + l]; b2 = eb[128 + l]; b3 = eb[192 + l];
    }
    int cn0 = cntL[0];
    int cn1 = (nw > 1) ? cntL[1] : 0;
    uint64_t s_cur = 0;                      // S[0] is all-zero

    for (int t = 0; t < nw; ++t) {
      // issue prefetch for tile t+2 (independent of everything below)
      uint64_t dw2 = 0; uint32_t c0 = 0, c1 = 0, c2 = 0, c3 = 0; int cn2 = 0;
      if (t + 2 < nw) {
        dw2 = diagArr[(size_t)(t + 2) * 64 + l];
        const uint32_t* eb = edgebuf + (size_t)(t + 2) * CAP;
        c0 = eb[l]; c1 = eb[64 + l]; c2 = eb[128 + l]; c3 = eb[192 + l];
        cn2 = cntL[t + 2];
      }

      uint64_t kw = ~s_cur;
      int rem = N - t * 64;
      if (rem < 64) kw &= ((1ull << rem) - 1ull);

      uint64_t m = __ballot(dw0 != 0ull);    // sparse: ~0-1 bits typical
      while (m) {
        int b = __builtin_ctzll(m);
        m &= m - 1;
        if ((kw >> b) & 1ull) kw &= ~shfl_u64(dw0, b);
      }
      if (l == 0) keepL[t] = kw;

      // apply this tile's edges, predicated on final kw
      int c = cn0 < CAP ? cn0 : CAP;
      uint32_t ee[4] = {a0, a1, a2, a3};
      #pragma unroll
      for (int k = 0; k < 4; ++k) {
        int idx = 64 * k + l;
        if (idx < c) {
          int b = (int)(ee[k] >> 16), j = (int)(ee[k] & 0xFFFFu);
          if ((kw >> b) & 1ull)
            atomicOr(&S[2 * (j >> 6) + ((j >> 5) & 1)], 1u << (j & 31));
        }
      }
      if (c > 256) {                          // overflow path (expected never)
        const uint32_t* eb = edgebuf + (size_t)t * CAP;
        for (int k2 = 256 + l; k2 < c; k2 += 64) {
          uint32_t e = eb[k2];
          int b = (int)(e >> 16), j = (int)(e & 0xFFFFu);
          if ((kw >> b) & 1ull)
            atomicOr(&S[2 * (j >> 6) + ((j >> 5) & 1)], 1u << (j & 31));
        }
      }

      // order LDS atomics before the S[t+1] read WITHOUT draining vmcnt:
      asm volatile("s_waitcnt lgkmcnt(0)" ::: "memory");
      if (t + 1 < nw)
        s_cur = ((uint64_t)S[2 * t + 3] << 32) | (uint64_t)S[2 * t + 2];

      // rotate prefetch registers
      dw0 = dw1; dw1 = dw2;
      a0 = b0; a1 = b1; a2 = b2; a3 = b3;
      b0 = c0; b1 = c1; b2 = c2; b3 = c3;
      cn0 = cn1; cn1 = cn2;
    }

    // exclusive popcount prefix over keep words (wave-parallel)
    uint64_t k0 = (l < nw)       ? keepL[l]       : 0ull;
    uint64_t k1 = (64 + l < nw)  ? keepL[64 + l]  : 0ull;
    uint64_t k2v = (128 + l < nw) ? keepL[128 + l] : 0ull;
    int p0 = __popcll(k0), p1 = __popcll(k1), p2 = __popcll(k2v);
    int s0 = p0, s1 = p1, s2 = p2;
    #pragma unroll
    for (int d = 1; d < 64; d <<= 1) {
      int v0 = __shfl_up(s0, d, 64), v1 = __shfl_up(s1, d, 64), v2 = __shfl_up(s2, d, 64);
      if (l >= d) { s0 += v0; s1 += v1; s2 += v2; }
    }
    int tot0 = __shfl(s0, 63, 64);
    int tot1 = __shfl(s1, 63, 64);
    wprefL[l] = s0 - p0;
    wprefL[64 + l] = tot0 + s1 - p1;
    if (128 + l < WPAD) wprefL[128 + l] = tot0 + tot1 + s2 - p2;
    if (l < nw && keepL[l] == 0 && false) {}  // keep compiler honest (no-op)
  } else {
    // non-scan waves: keepL entries beyond what wave 0 writes are never read
  }
  __syncthreads();

  // output phase: all 16 waves. Layout: boxes (N*4) | scores (N) | keep (N).
  float4* bo = (float4*)out;
  float* so = out + (size_t)4 * N;
  float* ko = so + N;
  for (int i = tid; i < N; i += 1024) {
    int w = i >> 6, b = i & 63;
    uint64_t kwv = keepL[w];
    bool kept = (kwv >> b) & 1ull;
    int rank = wprefL[w] + __popcll(kwv & ((1ull << b) - 1ull));
    bool fin = kept && (rank < MAX_PROPOSALS);
    float4 bx = sbox[i];
    if (!fin) { bx.x = 0.0f; bx.y = 0.0f; bx.z = 0.0f; bx.w = 0.0f; }
    bo[i] = bx;
    so[i] = fin ? ss[i] : 0.0f;
    ko[i] = fin ? 1.0f : 0.0f;
  }
}

extern "C" void kernel_launch(void* const* d_in, const int* in_sizes, int n_in,
                              void* d_out, int out_size, void* d_ws, size_t ws_size,
                              hipStream_t stream) {
  const float* boxes  = (const float*)d_in[0];
  const float* scores = (const float*)d_in[1];
  int N = in_sizes[1];
  int W = (N + 63) >> 6;            // 157 for N=10000; layout requires W <= WPAD

  char* ws = (char*)d_ws;
  size_t off = 0;
  float4* sbox = (float4*)(ws + off); off += (size_t)N * 16;
  float* ss    = (float*)(ws + off);  off += (size_t)N * 4;
  off = (off + 255) & ~(size_t)255;
  int* rank2d = (int*)(ws + off); off += (size_t)JCH * N * 4;
  off = (off + 255) & ~(size_t)255;
  uint64_t* diagArr = (uint64_t*)(ws + off); off += (size_t)WPAD * 64 * 8;
  uint32_t* edgebuf = (uint32_t*)(ws + off); off += (size_t)WPAD * CAP * 4;
  int* tcnt = (int*)(ws + off); off += (size_t)WPAD * 4;

  int nblk = (N + 255) / 256;
  int chunk = (N + JCH - 1) / JCH;

  k_rank<<<dim3(nblk, JCH), 256, (size_t)chunk * sizeof(float), stream>>>(scores, rank2d, tcnt, N);
  k_scatter<<<nblk, 256, 0, stream>>>((const float4*)boxes, scores, rank2d, sbox, ss, N);

  dim3 mg((W + 3) / 4, W);
  k_mask2<<<mg, 256, 0, stream>>>(sbox, diagArr, edgebuf, tcnt, N, W);

  k_scan6<<<1, 1024, 0, stream>>>(diagArr, edgebuf, tcnt, sbox, ss, (float*)d_out, N);
}

// Round 6
// 207.894 us; speedup vs baseline: 22.4732x; 1.0734x over previous
//
#include <hip/hip_runtime.h>
#include <stdint.h>

#define MAX_PROPOSALS 1000
#define WPAD 160      // static bound on 64-bit word count; requires W <= 160
#define JCH 16        // j-chunks for the rank phase
#define CAP 2048      // per-TARGET-tile edge capacity (expected ~60, huge margin)
#define FASTE 128     // edges handled in the prefetched fast path per tile

__device__ __forceinline__ uint64_t shfl_u64(uint64_t v, int lane) {
  int lo = __shfl((int)(unsigned int)v, lane, 64);
  int hi = __shfl((int)(unsigned int)(v >> 32), lane, 64);
  return ((uint64_t)(unsigned int)hi << 32) | (uint64_t)(unsigned int)lo;
}

// ---------------------------------------------------------------------------
// K1a: partial rank counts (stable argsort by descending score) with PACKED
// u64 keys: key = (score_bits<<32) | (0xFFFFFFFF - j). Positive-float bits
// are order-isomorphic, so key_j > key_i  <=>  (s_j > s_i) || (s_j==s_i && j<i).
// One u64 compare per pair. Also zero-inits tcnt cursors.
// ---------------------------------------------------------------------------
__global__ __launch_bounds__(256) void k_rank(const float* __restrict__ scores,
                                              int* __restrict__ rank2d,
                                              int* __restrict__ tcnt, int N) {
  if (blockIdx.x == 0 && blockIdx.y == 0 && threadIdx.x < WPAD) tcnt[threadIdx.x] = 0;
  int jc = blockIdx.y;
  int chunk = (N + JCH - 1) / JCH;
  int j0 = jc * chunk;
  int j1 = min(N, j0 + chunk);
  extern __shared__ uint64_t shk[];
  for (int j = j0 + threadIdx.x; j < j1; j += 256) {
    uint32_t b = __float_as_uint(scores[j]);
    shk[j - j0] = ((uint64_t)b << 32) | (uint64_t)(0xFFFFFFFFu - (uint32_t)j);
  }
  __syncthreads();
  int i = blockIdx.x * 256 + threadIdx.x;
  if (i >= N) return;
  uint64_t ki = ((uint64_t)__float_as_uint(scores[i]) << 32) | (uint64_t)(0xFFFFFFFFu - (uint32_t)i);
  int r = 0;
  int j = j0;
  for (; j + 4 <= j1; j += 4) {
    uint64_t A = shk[j - j0], B = shk[j - j0 + 1], C = shk[j - j0 + 2], D = shk[j - j0 + 3];
    r += (A > ki);
    r += (B > ki);
    r += (C > ki);
    r += (D > ki);
  }
  for (; j < j1; ++j) r += (shk[j - j0] > ki);
  rank2d[(size_t)jc * N + i] = r;
}

// K1b: sum partial ranks, scatter boxes (as float4) + scores into sorted order.
__global__ __launch_bounds__(256) void k_scatter(const float4* __restrict__ boxes,
                       const float* __restrict__ scores, const int* __restrict__ rank2d,
                       float4* __restrict__ sbox, float* __restrict__ ss, int N) {
  int i = blockIdx.x * 256 + threadIdx.x;
  if (i >= N) return;
  int r = 0;
  #pragma unroll
  for (int c = 0; c < JCH; ++c) r += rank2d[(size_t)c * N + i];
  sbox[r] = boxes[i];
  ss[r]   = scores[i];
}

// ---------------------------------------------------------------------------
// K2: sparse suppression graph, edges bucketed BY TARGET word.
// Triangular linearized grid: wave handles pair L=(cb,rb), rb<=cb — no empty
// waves. Lane = column; rows broadcast via readlane; per-row word via ballot.
// rb==cb -> diagArr; rb<cb -> entries (src_abs<<6)|bitpos appended to the
// TARGET tile's list (tcnt[cb] cursor).
// IoU decision: inter > 0.5*m (exact); true-division fallback gated behind a
// wave-uniform ballot so the IEEE div can never be if-converted into the loop.
// ---------------------------------------------------------------------------
__global__ __launch_bounds__(256) void k_mask3(const float4* __restrict__ sbox,
                        uint64_t* __restrict__ diagArr, uint32_t* __restrict__ edgebuf,
                        int* __restrict__ tcnt, int N, int W, int T) {
  int wv = threadIdx.x >> 6, lane = threadIdx.x & 63;
  int L = blockIdx.x * 4 + wv;
  if (L >= T) return;
  // invert triangular index: L = cb*(cb+1)/2 + rb, rb in [0,cb]
  int cb = (int)((sqrtf(8.0f * (float)L + 1.0f) - 1.0f) * 0.5f);
  while ((cb + 1) * (cb + 2) / 2 <= L) ++cb;
  while (cb * (cb + 1) / 2 > L) --cb;
  int rb = L - cb * (cb + 1) / 2;

  int row = rb * 64 + lane;          // this lane's ROW (data + word owner)
  int c   = cb * 64 + lane;          // this lane's COLUMN (IoU lane)
  int rl = min(row, N - 1), cl = min(c, N - 1);
  float4 rB = sbox[rl];
  float rar = (rB.z - rB.x) * (rB.w - rB.y);
  float4 cB = sbox[cl];
  float car = (cB.z - cB.x) * (cB.w - cB.y);

  uint64_t myw = 0;
  #pragma unroll 8
  for (int i = 0; i < 64; ++i) {
    float x1 = __int_as_float(__builtin_amdgcn_readlane(__float_as_int(rB.x), i));
    float y1 = __int_as_float(__builtin_amdgcn_readlane(__float_as_int(rB.y), i));
    float x2 = __int_as_float(__builtin_amdgcn_readlane(__float_as_int(rB.z), i));
    float y2 = __int_as_float(__builtin_amdgcn_readlane(__float_as_int(rB.w), i));
    float ar = __int_as_float(__builtin_amdgcn_readlane(__float_as_int(rar), i));
    float ix1 = fmaxf(x1, cB.x);
    float iy1 = fmaxf(y1, cB.y);
    float ix2 = fminf(x2, cB.z);
    float iy2 = fminf(y2, cB.w);
    float iw = fmaxf(ix2 - ix1, 0.0f);
    float ih = fmaxf(iy2 - iy1, 0.0f);
    float inter = iw * ih;
    float uni = (ar + car) - inter;
    float m_ = fmaxf(uni, 1e-9f);
    float t_ = 0.5f * m_;                 // exact (power-of-two scale)
    bool pred = inter > t_;               // == (inter/m_ > 0.5) except 1-ulp window
    bool ambig = pred && (inter <= t_ + t_ * 3e-7f);
    if (__builtin_expect(__ballot(ambig) != 0ull, 0)) {
      if (ambig) pred = (inter / m_) > 0.5f;   // exact reference op, cold path
    }
    int rowi = rb * 64 + i;
    bool bit = pred && (c > rowi) && (c < N);
    uint64_t ball = __ballot(bit);
    if (lane == i) myw = ball;
  }

  if (rb == cb) {
    diagArr[(size_t)rb * 64 + lane] = myw;     // in-tile j>i bits
  } else if (row < N) {
    uint64_t w = myw;
    while (w) {
      int jj = __builtin_ctzll(w);
      w &= w - 1;
      int pos = atomicAdd(&tcnt[cb], 1);
      if (pos < CAP) edgebuf[(size_t)cb * CAP + pos] = ((uint32_t)row << 6) | (uint32_t)jj;
    }
  }
}

// ---------------------------------------------------------------------------
// K3: scan + output, ONE block of 1024. Wave 0 runs the greedy scan with
// TARGET-bucketed edges: at tile t every incoming edge's source word is
// already decided, so the per-tile work is
//   gather keepL[src>>6] (LDS) -> test src bit -> atomicOr into a per-tile
//   2-word accumulator -> lgkm fence -> read accumulator -> diag chain -> kw.
// No cross-tile S scatter, no vmcnt on the chain (edges/diag prefetched
// depth-2 in registers). Then one __syncthreads and all 16 waves write the
// output (boxes | scores | keep).
// ---------------------------------------------------------------------------
__global__ __launch_bounds__(1024) void k_scan7(const uint64_t* __restrict__ diagArr,
                                                const uint32_t* __restrict__ edgebuf,
                                                const int* __restrict__ tcnt,
                                                const float4* __restrict__ sbox,
                                                const float* __restrict__ ss,
                                                float* __restrict__ out, int N) {
  const int tid = threadIdx.x, l = tid & 63, wave = tid >> 6;
  const int nw = (N + 63) >> 6;

  __shared__ uint32_t suppA[2 * WPAD];   // per-tile incoming-suppression accum
  __shared__ uint64_t keepL[WPAD];       // keep words (LDS source of truth)
  __shared__ int cntL[WPAD];
  __shared__ int wprefL[WPAD];

  for (int i = tid; i < 2 * WPAD; i += 1024) suppA[i] = 0u;
  for (int i = tid; i < WPAD; i += 1024) {
    keepL[i] = 0ull;
    cntL[i] = (i < nw) ? tcnt[i] : 0;
  }
  __syncthreads();

  if (wave == 0) {
    // depth-2 register prefetch of diag + fast-path edges
    uint64_t dw0 = diagArr[l];
    uint32_t a0 = edgebuf[l], a1 = edgebuf[64 + l];
    uint64_t dw1 = 0; uint32_t b0 = 0, b1 = 0;
    if (nw > 1) {
      dw1 = diagArr[64 + l];
      const uint32_t* eb = edgebuf + CAP;
      b0 = eb[l]; b1 = eb[64 + l];
    }
    int cn0 = cntL[0];
    int cn1 = (nw > 1) ? cntL[1] : 0;

    for (int t = 0; t < nw; ++t) {
      // issue prefetch for tile t+2 (never fenced; vmcnt stays in flight)
      uint64_t dw2 = 0; uint32_t c0 = 0, c1 = 0; int cn2 = 0;
      if (t + 2 < nw) {
        dw2 = diagArr[(size_t)(t + 2) * 64 + l];
        const uint32_t* eb = edgebuf + (size_t)(t + 2) * CAP;
        c0 = eb[l]; c1 = eb[64 + l];
        cn2 = cntL[t + 2];
      }

      // incoming-edge gather (sources all decided: src word < t)
      int c = cn0 < FASTE ? cn0 : FASTE;
      if (l < c) {
        uint32_t e = a0;
        int src = (int)(e >> 6), bit = (int)(e & 63u);
        uint64_t kwsrc = keepL[(src >> 6) & (WPAD - 1)];
        if ((kwsrc >> (src & 63)) & 1ull)
          atomicOr(&suppA[2 * t + (bit >> 5)], 1u << (bit & 31));
      }
      if (64 + l < c) {
        uint32_t e = a1;
        int src = (int)(e >> 6), bit = (int)(e & 63u);
        uint64_t kwsrc = keepL[(src >> 6) & (WPAD - 1)];
        if ((kwsrc >> (src & 63)) & 1ull)
          atomicOr(&suppA[2 * t + (bit >> 5)], 1u << (bit & 31));
      }
      if (__builtin_expect(cn0 > FASTE, 0)) {     // overflow path (rare)
        const uint32_t* eb = edgebuf + (size_t)t * CAP;
        int ce = cn0 < CAP ? cn0 : CAP;
        for (int k = FASTE + l; k < ce; k += 64) {
          uint32_t e = eb[k];
          int src = (int)(e >> 6), bit = (int)(e & 63u);
          uint64_t kwsrc = keepL[(src >> 6) & (WPAD - 1)];
          if ((kwsrc >> (src & 63)) & 1ull)
            atomicOr(&suppA[2 * t + (bit >> 5)], 1u << (bit & 31));
        }
      }

      // order LDS atomics before the accumulator read (lgkm only — global
      // prefetch loads stay outstanding)
      asm volatile("s_waitcnt lgkmcnt(0)" ::: "memory");
      uint64_t supp = ((uint64_t)suppA[2 * t + 1] << 32) | (uint64_t)suppA[2 * t];

      uint64_t kw = ~supp;
      int rem = N - t * 64;
      if (rem < 64) kw &= ((1ull << rem) - 1ull);

      uint64_t m = __ballot(dw0 != 0ull);         // sparse: ~0-1 bits typical
      while (m) {
        int b = __builtin_ctzll(m);
        m &= m - 1;
        if ((kw >> b) & 1ull) kw &= ~shfl_u64(dw0, b);
      }
      if (l == 0) keepL[t] = kw;                  // in-order DS: visible to
                                                  // this wave's later reads
      // rotate prefetch registers
      dw0 = dw1; dw1 = dw2;
      a0 = b0; a1 = b1;
      b0 = c0; b1 = c1;
      cn0 = cn1; cn1 = cn2;
    }

    // exclusive popcount prefix over keep words (wave-parallel)
    asm volatile("s_waitcnt lgkmcnt(0)" ::: "memory");
    uint64_t k0 = keepL[l], k1 = keepL[64 + l];
    uint64_t k2v = (128 + l < WPAD) ? keepL[128 + l] : 0ull;
    int p0 = __popcll(k0), p1 = __popcll(k1), p2 = __popcll(k2v);
    int s0 = p0, s1 = p1, s2 = p2;
    #pragma unroll
    for (int d = 1; d < 64; d <<= 1) {
      int v0 = __shfl_up(s0, d, 64), v1 = __shfl_up(s1, d, 64), v2 = __shfl_up(s2, d, 64);
      if (l >= d) { s0 += v0; s1 += v1; s2 += v2; }
    }
    int tot0 = __shfl(s0, 63, 64);
    int tot1 = __shfl(s1, 63, 64);
    wprefL[l] = s0 - p0;
    wprefL[64 + l] = tot0 + s1 - p1;
    if (128 + l < WPAD) wprefL[128 + l] = tot0 + tot1 + s2 - p2;
  }
  __syncthreads();

  // output phase: all 16 waves. Layout: boxes (N*4) | scores (N) | keep (N).
  float4* bo = (float4*)out;
  float* so = out + (size_t)4 * N;
  float* ko = so + N;
  for (int i = tid; i < N; i += 1024) {
    int w = i >> 6, b = i & 63;
    uint64_t kwv = keepL[w];
    bool kept = (kwv >> b) & 1ull;
    int rank = wprefL[w] + __popcll(kwv & ((1ull << b) - 1ull));
    bool fin = kept && (rank < MAX_PROPOSALS);
    float4 bx = sbox[i];
    if (!fin) { bx.x = 0.0f; bx.y = 0.0f; bx.z = 0.0f; bx.w = 0.0f; }
    bo[i] = bx;
    so[i] = fin ? ss[i] : 0.0f;
    ko[i] = fin ? 1.0f : 0.0f;
  }
}

extern "C" void kernel_launch(void* const* d_in, const int* in_sizes, int n_in,
                              void* d_out, int out_size, void* d_ws, size_t ws_size,
                              hipStream_t stream) {
  const float* boxes  = (const float*)d_in[0];
  const float* scores = (const float*)d_in[1];
  int N = in_sizes[1];
  int W = (N + 63) >> 6;            // 157 for N=10000; layout requires W <= WPAD
  int T = W * (W + 1) / 2;          // upper-triangle tile-pairs

  char* ws = (char*)d_ws;
  size_t off = 0;
  float4* sbox = (float4*)(ws + off); off += (size_t)N * 16;
  float* ss    = (float*)(ws + off);  off += (size_t)N * 4;
  off = (off + 255) & ~(size_t)255;
  int* rank2d = (int*)(ws + off); off += (size_t)JCH * N * 4;
  off = (off + 255) & ~(size_t)255;
  uint64_t* diagArr = (uint64_t*)(ws + off); off += (size_t)WPAD * 64 * 8;
  uint32_t* edgebuf = (uint32_t*)(ws + off); off += (size_t)WPAD * CAP * 4;
  int* tcnt = (int*)(ws + off); off += (size_t)WPAD * 4;

  int nblk = (N + 255) / 256;
  int chunk = (N + JCH - 1) / JCH;

  k_rank<<<dim3(nblk, JCH), 256, (size_t)chunk * sizeof(uint64_t), stream>>>(scores, rank2d, tcnt, N);
  k_scatter<<<nblk, 256, 0, stream>>>((const float4*)boxes, scores, rank2d, sbox, ss, N);

  k_mask3<<<(T + 3) / 4, 256, 0, stream>>>(sbox, diagArr, edgebuf, tcnt, N, W, T);

  k_scan7<<<1, 1024, 0, stream>>>(diagArr, edgebuf, tcnt, sbox, ss, (float*)d_out, N);
}

// Round 7
// 148.844 us; speedup vs baseline: 31.3889x; 1.3967x over previous
//
#include <hip/hip_runtime.h>
#include <stdint.h>

#define MAX_PROPOSALS 1000
#define WPAD 160        // static bound on 64-bit word count; requires W <= 160
#define JCH 16          // j-chunks for the rank phase
#define EMAX (1 << 19)  // flat edge-list capacity (~23k expected; 20x margin)

// ---------------------------------------------------------------------------
// K1a: partial rank counts (stable argsort by descending score) with PACKED
// u64 keys: key = (score_bits<<32) | (0xFFFFFFFF - j). Positive-float bits
// are order-isomorphic, so key_j > key_i  <=>  (s_j > s_i) || (s_j==s_i && j<i).
// Also zero-inits the edge counter.
// ---------------------------------------------------------------------------
__global__ __launch_bounds__(256) void k_rank(const float* __restrict__ scores,
                                              int* __restrict__ rank2d,
                                              int* __restrict__ ecnt, int N) {
  if (blockIdx.x == 0 && blockIdx.y == 0 && threadIdx.x == 0) *ecnt = 0;
  int jc = blockIdx.y;
  int chunk = (N + JCH - 1) / JCH;
  int j0 = jc * chunk;
  int j1 = min(N, j0 + chunk);
  extern __shared__ uint64_t shk[];
  for (int j = j0 + threadIdx.x; j < j1; j += 256) {
    uint32_t b = __float_as_uint(scores[j]);
    shk[j - j0] = ((uint64_t)b << 32) | (uint64_t)(0xFFFFFFFFu - (uint32_t)j);
  }
  __syncthreads();
  int i = blockIdx.x * 256 + threadIdx.x;
  if (i >= N) return;
  uint64_t ki = ((uint64_t)__float_as_uint(scores[i]) << 32) | (uint64_t)(0xFFFFFFFFu - (uint32_t)i);
  int r = 0;
  int j = j0;
  for (; j + 4 <= j1; j += 4) {
    uint64_t A = shk[j - j0], B = shk[j - j0 + 1], C = shk[j - j0 + 2], D = shk[j - j0 + 3];
    r += (A > ki);
    r += (B > ki);
    r += (C > ki);
    r += (D > ki);
  }
  for (; j < j1; ++j) r += (shk[j - j0] > ki);
  rank2d[(size_t)jc * N + i] = r;
}

// K1b: sum partial ranks, scatter boxes (as float4) + scores into sorted order.
__global__ __launch_bounds__(256) void k_scatter(const float4* __restrict__ boxes,
                       const float* __restrict__ scores, const int* __restrict__ rank2d,
                       float4* __restrict__ sbox, float* __restrict__ ss, int N) {
  int i = blockIdx.x * 256 + threadIdx.x;
  if (i >= N) return;
  int r = 0;
  #pragma unroll
  for (int c = 0; c < JCH; ++c) r += rank2d[(size_t)c * N + i];
  sbox[r] = boxes[i];
  ss[r]   = scores[i];
}

// ---------------------------------------------------------------------------
// K2: sparse IoU graph as ONE flat edge list (no ordering needed by Jacobi).
// Triangular linearized grid: wave = tile-pair (rb<=cb). Lane = column; rows
// broadcast via readlane; per-row word via ballot. Edges (i<<14|j), i<j,
// appended with a wave-aggregated cursor (prefix scan + 1 atomicAdd/wave).
// IoU decision: inter > 0.5*uni (exact for >0.5 semantics since 0.5*m is a
// power-of-two scale); true-division fallback gated wave-uniformly.
// ---------------------------------------------------------------------------
__global__ __launch_bounds__(256) void k_mask4(const float4* __restrict__ sbox,
                        uint32_t* __restrict__ edges, int* __restrict__ ecnt,
                        int N, int W, int T) {
  int wv = threadIdx.x >> 6, lane = threadIdx.x & 63;
  int L = blockIdx.x * 4 + wv;
  if (L >= T) return;
  // invert triangular index: L = cb*(cb+1)/2 + rb, rb in [0,cb]
  int cb = (int)((sqrtf(8.0f * (float)L + 1.0f) - 1.0f) * 0.5f);
  while ((cb + 1) * (cb + 2) / 2 <= L) ++cb;
  while (cb * (cb + 1) / 2 > L) --cb;
  int rb = L - cb * (cb + 1) / 2;

  int row = rb * 64 + lane;          // this lane's ROW (data + word owner)
  int c   = cb * 64 + lane;          // this lane's COLUMN (IoU lane)
  int rl = min(row, N - 1), cl = min(c, N - 1);
  float4 rB = sbox[rl];
  float rar = (rB.z - rB.x) * (rB.w - rB.y);
  float4 cB = sbox[cl];
  float car = (cB.z - cB.x) * (cB.w - cB.y);

  uint64_t myw = 0;
  #pragma unroll 8
  for (int i = 0; i < 64; ++i) {
    float x1 = __int_as_float(__builtin_amdgcn_readlane(__float_as_int(rB.x), i));
    float y1 = __int_as_float(__builtin_amdgcn_readlane(__float_as_int(rB.y), i));
    float x2 = __int_as_float(__builtin_amdgcn_readlane(__float_as_int(rB.z), i));
    float y2 = __int_as_float(__builtin_amdgcn_readlane(__float_as_int(rB.w), i));
    float ar = __int_as_float(__builtin_amdgcn_readlane(__float_as_int(rar), i));
    float ix1 = fmaxf(x1, cB.x);
    float iy1 = fmaxf(y1, cB.y);
    float ix2 = fminf(x2, cB.z);
    float iy2 = fminf(y2, cB.w);
    float iw = fmaxf(ix2 - ix1, 0.0f);
    float ih = fmaxf(iy2 - iy1, 0.0f);
    float inter = iw * ih;
    float uni = (ar + car) - inter;
    float m_ = fmaxf(uni, 1e-9f);
    float t_ = 0.5f * m_;                 // exact (power-of-two scale)
    bool pred = inter > t_;               // == (inter/m_ > 0.5) except 1-ulp window
    bool ambig = pred && (inter <= t_ + t_ * 3e-7f);
    if (__builtin_expect(__ballot(ambig) != 0ull, 0)) {
      if (ambig) pred = (inter / m_) > 0.5f;   // exact reference op, cold path
    }
    int rowi = rb * 64 + i;
    bool bit = pred && (c > rowi) && (c < N);
    uint64_t ball = __ballot(bit);
    if (lane == i) myw = ball;
  }

  // wave-aggregated append of this wave's edges
  int ne = (row < N) ? __popcll(myw) : 0;
  int pre = ne;
  #pragma unroll
  for (int d = 1; d < 64; d <<= 1) {
    int v = __shfl_up(pre, d, 64);
    if (lane >= d) pre += v;
  }
  int tot = __shfl(pre, 63, 64);
  int base = 0;
  if (lane == 63 && tot > 0) base = atomicAdd(ecnt, tot);
  base = __shfl(base, 63, 64);
  int pos = base + pre - ne;
  if (row < N) {
    uint64_t w = myw;
    while (w) {
      int jj = __builtin_ctzll(w);
      w &= w - 1;
      if (pos < EMAX) edges[pos] = ((uint32_t)row << 14) | (uint32_t)(cb * 64 + jj);
      ++pos;
    }
  }
}

// ---------------------------------------------------------------------------
// K3: Jacobi fixed-point NMS + output, ONE block of 1024 (16 waves, all busy).
// keep^{r+1}[j] = base[j] & ~OR_{(i->j)} keep^r[i]. Unique fixed point ==
// greedy NMS (induction on rank order); converges in DAG-depth+1 rounds
// (~5-20 here). Edges streamed from L2 each round; keep bits in LDS.
// Then popcount-prefix + MAX_PROPOSALS cutoff + output write.
// ---------------------------------------------------------------------------
__global__ __launch_bounds__(1024) void k_scanJ(const uint32_t* __restrict__ edges,
                                                const int* __restrict__ ecnt,
                                                const float4* __restrict__ sbox,
                                                const float* __restrict__ ss,
                                                float* __restrict__ out, int N) {
  const int tid = threadIdx.x, l = tid & 63, wave = tid >> 6;
  const int nw = (N + 63) >> 6;
  const int nh = 2 * nw;               // u32 half-words in use

  __shared__ uint32_t kc[2 * WPAD];    // keep, current generation
  __shared__ uint32_t kn[2 * WPAD];    // keep, next generation
  __shared__ uint32_t baseL[2 * WPAD]; // tail-masked all-ones template
  __shared__ uint64_t keepL[WPAD];
  __shared__ int wprefL[WPAD];
  __shared__ int chgS;

  for (int w = tid; w < 2 * WPAD; w += 1024) {
    long lo = (long)(w >> 1) * 64 + (long)(w & 1) * 32;
    long rem = (long)N - lo;
    uint32_t m = (rem >= 32) ? 0xFFFFFFFFu : ((rem <= 0) ? 0u : ((1u << rem) - 1u));
    baseL[w] = m;
    kc[w] = m;
  }
  __syncthreads();

  int E = *ecnt;                        // uniform scalar load
  if (E > EMAX) E = EMAX;

  for (int round = 0; round < 10001; ++round) {
    // init next generation + reset change flag
    for (int w = tid; w < nh; w += 1024) kn[w] = baseL[w];
    if (tid == 0) chgS = 0;
    __syncthreads();

    // apply all edges whose source is currently kept
    for (int e = tid; e < E; e += 1024) {
      uint32_t p = edges[e];
      int i = (int)(p >> 14);
      int j = (int)(p & 0x3FFFu);
      if ((kc[i >> 5] >> (i & 31)) & 1u)
        atomicAnd(&kn[j >> 5], ~(1u << (j & 31)));
    }
    __syncthreads();

    // compare + copy next -> current
    int local = 0;
    for (int w = tid; w < nh; w += 1024) {
      uint32_t a = kn[w];
      if (a != kc[w]) local = 1;
      kc[w] = a;
    }
    if (local) chgS = 1;
    __syncthreads();
    bool done = (chgS == 0);
    __syncthreads();                    // everyone reads chgS before reset
    if (done) break;
  }

  // build u64 keep words
  for (int i = tid; i < WPAD; i += 1024)
    keepL[i] = (i < nw) ? (((uint64_t)kc[2 * i + 1] << 32) | (uint64_t)kc[2 * i]) : 0ull;
  __syncthreads();

  if (wave == 0) {
    // exclusive popcount prefix over keep words (wave-parallel)
    uint64_t k0 = keepL[l], k1 = keepL[64 + l];
    uint64_t k2v = (128 + l < WPAD) ? keepL[128 + l] : 0ull;
    int p0 = __popcll(k0), p1 = __popcll(k1), p2 = __popcll(k2v);
    int s0 = p0, s1 = p1, s2 = p2;
    #pragma unroll
    for (int d = 1; d < 64; d <<= 1) {
      int v0 = __shfl_up(s0, d, 64), v1 = __shfl_up(s1, d, 64), v2 = __shfl_up(s2, d, 64);
      if (l >= d) { s0 += v0; s1 += v1; s2 += v2; }
    }
    int tot0 = __shfl(s0, 63, 64);
    int tot1 = __shfl(s1, 63, 64);
    wprefL[l] = s0 - p0;
    wprefL[64 + l] = tot0 + s1 - p1;
    if (128 + l < WPAD) wprefL[128 + l] = tot0 + tot1 + s2 - p2;
  }
  __syncthreads();

  // output phase: all 16 waves. Layout: boxes (N*4) | scores (N) | keep (N).
  float4* bo = (float4*)out;
  float* so = out + (size_t)4 * N;
  float* ko = so + N;
  for (int i = tid; i < N; i += 1024) {
    int w = i >> 6, b = i & 63;
    uint64_t kwv = keepL[w];
    bool kept = (kwv >> b) & 1ull;
    int rank = wprefL[w] + __popcll(kwv & ((1ull << b) - 1ull));
    bool fin = kept && (rank < MAX_PROPOSALS);
    float4 bx = sbox[i];
    if (!fin) { bx.x = 0.0f; bx.y = 0.0f; bx.z = 0.0f; bx.w = 0.0f; }
    bo[i] = bx;
    so[i] = fin ? ss[i] : 0.0f;
    ko[i] = fin ? 1.0f : 0.0f;
  }
}

extern "C" void kernel_launch(void* const* d_in, const int* in_sizes, int n_in,
                              void* d_out, int out_size, void* d_ws, size_t ws_size,
                              hipStream_t stream) {
  const float* boxes  = (const float*)d_in[0];
  const float* scores = (const float*)d_in[1];
  int N = in_sizes[1];
  int W = (N + 63) >> 6;            // 157 for N=10000; layout requires W <= WPAD
  int T = W * (W + 1) / 2;          // upper-triangle tile-pairs

  char* ws = (char*)d_ws;
  size_t off = 0;
  float4* sbox = (float4*)(ws + off); off += (size_t)N * 16;
  float* ss    = (float*)(ws + off);  off += (size_t)N * 4;
  off = (off + 255) & ~(size_t)255;
  int* rank2d = (int*)(ws + off); off += (size_t)JCH * N * 4;
  off = (off + 255) & ~(size_t)255;
  uint32_t* edges = (uint32_t*)(ws + off); off += (size_t)EMAX * 4;
  int* ecnt = (int*)(ws + off); off += 256;

  int nblk = (N + 255) / 256;
  int chunk = (N + JCH - 1) / JCH;

  k_rank<<<dim3(nblk, JCH), 256, (size_t)chunk * sizeof(uint64_t), stream>>>(scores, rank2d, ecnt, N);
  k_scatter<<<nblk, 256, 0, stream>>>((const float4*)boxes, scores, rank2d, sbox, ss, N);

  k_mask4<<<(T + 3) / 4, 256, 0, stream>>>(sbox, edges, ecnt, N, W, T);

  k_scanJ<<<1, 1024, 0, stream>>>(edges, ecnt, sbox, ss, (float*)d_out, N);
}